// Round 4
// baseline (1134.266 us; speedup 1.0000x reference)
//
#include <hip/hip_runtime.h>
#include <hip/hip_bf16.h>

// AttentivePredictionFusion: B=8, T=2048, D=512, H=128.
// Inputs fp32; OUTPUT fp32 (R3 post-mortem: error==max|ref| exactly <=> second
// half of a 32MB f32 d_out untouched by a 16MB bf16 store. Reference returns
// fp32; harness maps non-bf16 outputs to float*).
// Pipeline: q/k/v GEMMs -> batched QK^T -> row softmax -> batched PV ->
//           dual-A fusion GEMM (+bias, sigmoid, f32 store).

#define APF_B 8
#define APF_T 2048
#define APF_D 512
#define APF_H 128
#define APF_M (APF_B * APF_T)   // 16384 rows total

// 128x128x16 tile, 256 threads, 8x8 accumulator per thread.
#define TBM 128
#define TBN 128
#define TBK 16

// DUAL_A: 0 = single fp32 A; 1 = concat A (k<APF_D from A1, else A2 at col-APF_D)
// BT:     0 = B is [K,N] row-major; 1 = B is [N,K] row-major (QK^T)
// SIGOUT: 0 = plain f32 store; 1 = bias+sigmoid+f32 store
template <int DUAL_A, int BT, int SIGOUT>
__global__ __launch_bounds__(256) void apf_gemm(
    const float* __restrict__ Ap, const float* __restrict__ A2p, long lda,
    const float* __restrict__ Bp, long ldb,
    const float* __restrict__ biasp,
    float* __restrict__ Cp, long ldc, int K,
    long sA, long sB, long sC)
{
    __shared__ float smA[TBK][TBM];
    __shared__ float smB[TBK][TBN];

    const int tid = threadIdx.x;
    const long row0 = (long)blockIdx.y * TBM;
    const long col0 = (long)blockIdx.x * TBN;
    const long zb   = blockIdx.z;

    float acc[8][8];
#pragma unroll
    for (int i = 0; i < 8; ++i)
#pragma unroll
        for (int j = 0; j < 8; ++j) acc[i][j] = 0.0f;

    const int cg = tid & 15;   // column group  (8 cols each)
    const int rg = tid >> 4;   // row group     (8 rows each)

    for (int kb = 0; kb < K; kb += TBK) {
        // A tile: smA[k][m] = A[row0+m][kb+k]
#pragma unroll
        for (int rep = 0; rep < 2; ++rep) {
            const int li = tid + rep * 256;        // 0..511
            const int am = li >> 2;                // 0..127
            const int ak = (li & 3) * 4;           // 0,4,8,12
            const float* src;
            long ac;
            if (DUAL_A == 1 && (kb + ak) >= APF_D) {
                src = A2p + zb * sA;
                ac  = (long)kb + ak - APF_D;
            } else {
                src = Ap + zb * sA;
                ac  = (long)kb + ak;
            }
            const float4 t = *(const float4*)(src + (row0 + am) * lda + ac);
            smA[ak + 0][am] = t.x;
            smA[ak + 1][am] = t.y;
            smA[ak + 2][am] = t.z;
            smA[ak + 3][am] = t.w;
        }
        // B tile
        if (BT == 0) {
#pragma unroll
            for (int rep = 0; rep < 2; ++rep) {
                const int li = tid + rep * 256;
                const int bk = li >> 5;            // 0..15
                const int bn = (li & 31) * 4;      // 0..124
                const float* src = Bp + zb * sB;
                const float4 t = *(const float4*)(src + (long)(kb + bk) * ldb + col0 + bn);
                smB[bk][bn + 0] = t.x;
                smB[bk][bn + 1] = t.y;
                smB[bk][bn + 2] = t.z;
                smB[bk][bn + 3] = t.w;
            }
        } else {
#pragma unroll
            for (int rep = 0; rep < 2; ++rep) {
                const int li = tid + rep * 256;
                const int bn = li >> 2;            // 0..127
                const int bk = (li & 3) * 4;       // 0,4,8,12
                const float* src = Bp + zb * sB;
                const float4 t = *(const float4*)(src + (col0 + bn) * ldb + kb + bk);
                smB[bk + 0][bn] = t.x;
                smB[bk + 1][bn] = t.y;
                smB[bk + 2][bn] = t.z;
                smB[bk + 3][bn] = t.w;
            }
        }
        __syncthreads();

#pragma unroll
        for (int kk = 0; kk < TBK; ++kk) {
            float ar[8], br[8];
            *(float4*)&ar[0] = *(const float4*)&smA[kk][rg * 8];
            *(float4*)&ar[4] = *(const float4*)&smA[kk][rg * 8 + 4];
            *(float4*)&br[0] = *(const float4*)&smB[kk][cg * 8];
            *(float4*)&br[4] = *(const float4*)&smB[kk][cg * 8 + 4];
#pragma unroll
            for (int i = 0; i < 8; ++i)
#pragma unroll
                for (int j = 0; j < 8; ++j)
                    acc[i][j] = fmaf(ar[i], br[j], acc[i][j]);
        }
        __syncthreads();
    }

    // epilogue
#pragma unroll
    for (int i = 0; i < 8; ++i) {
        const long r = row0 + rg * 8 + i;
#pragma unroll
        for (int jq = 0; jq < 2; ++jq) {
            const long c = col0 + cg * 8 + jq * 4;
            float e0 = acc[i][jq * 4 + 0];
            float e1 = acc[i][jq * 4 + 1];
            float e2 = acc[i][jq * 4 + 2];
            float e3 = acc[i][jq * 4 + 3];
            if (biasp != nullptr) {
                e0 += biasp[c + 0];
                e1 += biasp[c + 1];
                e2 += biasp[c + 2];
                e3 += biasp[c + 3];
            }
            if (SIGOUT == 1) {
                e0 = 1.0f / (1.0f + expf(-e0));
                e1 = 1.0f / (1.0f + expf(-e1));
                e2 = 1.0f / (1.0f + expf(-e2));
                e3 = 1.0f / (1.0f + expf(-e3));
            }
            float* dst = Cp + zb * sC;
            *(float4*)(dst + r * ldc + c) = make_float4(e0, e1, e2, e3);
        }
    }
}

// In-place row softmax over APF_T=2048 entries. 256 threads, 8 elems each.
__global__ __launch_bounds__(256) void apf_softmax(float* __restrict__ S)
{
    float* rowp = S + (long)blockIdx.x * APF_T;
    const int tid = threadIdx.x;

    float4 a = *(const float4*)(rowp + tid * 4);
    float4 b = *(const float4*)(rowp + 1024 + tid * 4);

    float mx = fmaxf(fmaxf(fmaxf(a.x, a.y), fmaxf(a.z, a.w)),
                     fmaxf(fmaxf(b.x, b.y), fmaxf(b.z, b.w)));
#pragma unroll
    for (int off = 32; off > 0; off >>= 1)
        mx = fmaxf(mx, __shfl_xor(mx, off));

    __shared__ float wm[4];
    __shared__ float wsum[4];
    const int wv = tid >> 6;
    const int ln = tid & 63;
    if (ln == 0) wm[wv] = mx;
    __syncthreads();
    mx = fmaxf(fmaxf(wm[0], wm[1]), fmaxf(wm[2], wm[3]));

    a.x = expf(a.x - mx); a.y = expf(a.y - mx);
    a.z = expf(a.z - mx); a.w = expf(a.w - mx);
    b.x = expf(b.x - mx); b.y = expf(b.y - mx);
    b.z = expf(b.z - mx); b.w = expf(b.w - mx);

    float sm = a.x + a.y + a.z + a.w + b.x + b.y + b.z + b.w;
#pragma unroll
    for (int off = 32; off > 0; off >>= 1)
        sm += __shfl_xor(sm, off);
    if (ln == 0) wsum[wv] = sm;
    __syncthreads();
    sm = wsum[0] + wsum[1] + wsum[2] + wsum[3];

    const float inv = 1.0f / sm;
    a.x *= inv; a.y *= inv; a.z *= inv; a.w *= inv;
    b.x *= inv; b.y *= inv; b.z *= inv; b.w *= inv;

    *(float4*)(rowp + tid * 4) = a;
    *(float4*)(rowp + 1024 + tid * 4) = b;
}

extern "C" void kernel_launch(void* const* d_in, const int* in_sizes, int n_in,
                              void* d_out, int out_size, void* d_ws, size_t ws_size,
                              hipStream_t stream)
{
    (void)in_sizes; (void)n_in; (void)out_size; (void)ws_size;

    const float* x    = (const float*)d_in[0];  // [B,T,D] fp32
    const float* pred = (const float*)d_in[1];  // [B,T,D] fp32
    const float* Wq   = (const float*)d_in[2];  // [D,H]
    const float* bq   = (const float*)d_in[3];  // [H]
    const float* Wk   = (const float*)d_in[4];  // [D,H]
    const float* bk   = (const float*)d_in[5];  // [H]
    const float* Wv   = (const float*)d_in[6];  // [D,D]
    const float* bv   = (const float*)d_in[7];  // [D]
    const float* Wf   = (const float*)d_in[8];  // [2D,D]
    const float* bfu  = (const float*)d_in[9];  // [D]

    // Workspace (fp32): q[16384,128] k[16384,128] v[16384,512] att[16384,512]
    //                   scores[8,2048,2048]  -> 208 MB total
    float* wsp = (float*)d_ws;
    float* qb  = wsp;
    float* kb  = qb  + (long)APF_M * APF_H;
    float* vb  = kb  + (long)APF_M * APF_H;
    float* ab  = vb  + (long)APF_M * APF_D;
    float* scb = ab  + (long)APF_M * APF_D;

    const dim3 thr(256);

    // q = pred @ Wq + bq    [16384,512] x [512,128]
    apf_gemm<0, 0, 0><<<dim3(1, 128, 1), thr, 0, stream>>>(
        pred, nullptr, APF_D, Wq, APF_H, bq, qb, APF_H, APF_D, 0, 0, 0);
    // k = x @ Wk + bk
    apf_gemm<0, 0, 0><<<dim3(1, 128, 1), thr, 0, stream>>>(
        x, nullptr, APF_D, Wk, APF_H, bk, kb, APF_H, APF_D, 0, 0, 0);
    // v = x @ Wv + bv       [16384,512] x [512,512]
    apf_gemm<0, 0, 0><<<dim3(4, 128, 1), thr, 0, stream>>>(
        x, nullptr, APF_D, Wv, APF_D, bv, vb, APF_D, APF_D, 0, 0, 0);

    // scores[z] = q[z] @ k[z]^T   [2048,128] x [2048,128]^T
    apf_gemm<0, 1, 0><<<dim3(16, 16, 8), thr, 0, stream>>>(
        qb, nullptr, APF_H, kb, APF_H, nullptr, scb, APF_T, APF_H,
        (long)APF_T * APF_H, (long)APF_T * APF_H, (long)APF_T * APF_T);

    // softmax over each of the 16384 score rows
    apf_softmax<<<dim3(APF_M), thr, 0, stream>>>(scb);

    // att[z] = P[z] @ v[z]   [2048,2048] x [2048,512]
    apf_gemm<0, 0, 0><<<dim3(4, 16, 8), thr, 0, stream>>>(
        scb, nullptr, APF_T, vb, APF_D, nullptr, ab, APF_D, APF_T,
        (long)APF_T * APF_T, (long)APF_T * APF_D, (long)APF_T * APF_D);

    // out = sigmoid([pred | att] @ Wf + bf)   K=1024, f32 store
    apf_gemm<1, 0, 1><<<dim3(4, 128, 1), thr, 0, stream>>>(
        pred, ab, APF_D, Wf, APF_D, bfu, (float*)d_out, APF_D, 2 * APF_D, 0, 0, 0);
}

// Round 5
// 357.242 us; speedup vs baseline: 3.1751x; 3.1751x over previous
//
#include <hip/hip_runtime.h>
#include <hip/hip_bf16.h>

// AttentivePredictionFusion: B=8, T=2048, D=512, H=128. fp32 in, fp32 out.
// R5: all GEMMs moved to bf16 MFMA 16x16x32 (fp32 accum). Pre-convert
// x/pred -> bf16, weights -> transposed [N][K] bf16; q/k/v/scores/P/att kept
// bf16 in workspace; softmax in-place bf16. Final fusion GEMM: bias+sigmoid,
// fp32 store to d_out.

#define APF_B 8
#define APF_T 2048
#define APF_D 512
#define APF_H 128
#define APF_M (APF_B * APF_T)   // 16384

typedef unsigned short u16;
typedef __attribute__((ext_vector_type(8))) short short8;
typedef __attribute__((ext_vector_type(4))) float f32x4;

static __device__ __forceinline__ float bf2f(u16 u) {
    union { unsigned int i; float f; } w;
    w.i = ((unsigned int)u) << 16;
    return w.f;
}
static __device__ __forceinline__ u16 f2bf(float x) {
    union { float f; unsigned int u; } cv;
    cv.f = x;
    unsigned int u = cv.u + 0x7FFFu + ((cv.u >> 16) & 1u);  // RNE
    return (u16)(u >> 16);
}

// ---------------- prep kernels ----------------

// fp32 -> bf16, vectorized, grid-stride over n/4 float4s (n % 4 == 0)
__global__ __launch_bounds__(256) void cvt_bf16(const float* __restrict__ in,
                                                u16* __restrict__ out, long n4)
{
    long i = blockIdx.x * 256L + threadIdx.x;
    const long stride = (long)gridDim.x * 256L;
    for (; i < n4; i += stride) {
        const float4 v = ((const float4*)in)[i];
        ushort4 o;
        o.x = f2bf(v.x); o.y = f2bf(v.y); o.z = f2bf(v.z); o.w = f2bf(v.w);
        ((ushort4*)out)[i] = o;
    }
}

// W[K][N] fp32 -> Wt[N][K] bf16 (small weight matrices; L2-resident)
__global__ __launch_bounds__(256) void tr_bf16(const float* __restrict__ W,
                                               u16* __restrict__ Wt, int K, int N)
{
    const long idx = blockIdx.x * 256L + threadIdx.x;
    if (idx >= (long)K * N) return;
    const int n = (int)(idx / K);
    const int k = (int)(idx % K);
    Wt[idx] = f2bf(W[(long)k * N + n]);
}

// ---------------- MFMA GEMM ----------------
// A: bf16 [M][K] row-major (lda); DUAL=1: k<512 from A, k>=512 from A2 (both lda=512)
// B: bf16 [N][K] row-major (ldb)  (i.e. B^T, K-contiguous)
// EPI: 0 = bf16 store C[m][n] (+bias);  1 = bf16 TRANSPOSED store vT[b][n][ml] (+bias)
//      2 = fp32 sigmoid store C[m][n] (+bias)
// Tile 128x128, BK=32, 256 threads = 4 waves in 2x2, each wave 4x4 MFMA tiles.
template <int DUAL, int EPI>
__global__ __launch_bounds__(256) void mfma_gemm(
    const u16* __restrict__ Ap, const u16* __restrict__ A2p, long lda,
    const u16* __restrict__ Bp, long ldb,
    const float* __restrict__ biasp,
    void* __restrict__ Cp, long ldc, int K,
    long sA, long sB, long sC)
{
    __shared__ u16 smA[128 * 32];
    __shared__ u16 smB[128 * 32];

    const int tid  = threadIdx.x;
    const int lane = tid & 63;
    const int wid  = tid >> 6;
    const int wr   = wid >> 1;   // wave row (0..1) -> 64 rows
    const int wc   = wid & 1;    // wave col (0..1) -> 64 cols

    const long row0 = (long)blockIdx.y * 128;
    const long col0 = (long)blockIdx.x * 128;
    const long z    = blockIdx.z;

    const u16* Ab = Ap + z * sA;
    const u16* Bb = Bp + z * sB;

    f32x4 acc[4][4];
#pragma unroll
    for (int i = 0; i < 4; ++i)
#pragma unroll
        for (int j = 0; j < 4; ++j)
            acc[i][j] = (f32x4){0.f, 0.f, 0.f, 0.f};

    const int lrow = (lane >> 4) * 4;   // C/D: row group
    const int lcol = lane & 15;         // C/D: col
    const int q8   = (lane >> 4) * 8;   // A/B frag: k offset

    for (int kb = 0; kb < K; kb += 32) {
        // stage A tile [128][32] bf16, K-contiguous; 512 chunks of 8 bf16
#pragma unroll
        for (int rep = 0; rep < 2; ++rep) {
            const int c  = tid + rep * 256;
            const int r  = c >> 2;
            const int kc = (c & 3) * 8;
            const u16* src;
            if (DUAL == 1 && (kb + kc) >= APF_D) {
                src = A2p + (row0 + r) * lda + (kb + kc - APF_D);
            } else {
                src = Ab + (row0 + r) * lda + (kb + kc);
            }
            const uint4 t = *(const uint4*)src;
            *(uint4*)&smA[r * 32 + kc] = t;
        }
        // stage B tile [128][32] bf16 from B[N][K]
#pragma unroll
        for (int rep = 0; rep < 2; ++rep) {
            const int c  = tid + rep * 256;
            const int r  = c >> 2;
            const int kc = (c & 3) * 8;
            const uint4 t = *(const uint4*)(Bb + (col0 + r) * ldb + (kb + kc));
            *(uint4*)&smB[r * 32 + kc] = t;
        }
        __syncthreads();

        short8 av[4], bv4[4];
#pragma unroll
        for (int ti = 0; ti < 4; ++ti)
            av[ti] = *(const short8*)&smA[(wr * 64 + ti * 16 + lcol) * 32 + q8];
#pragma unroll
        for (int tj = 0; tj < 4; ++tj)
            bv4[tj] = *(const short8*)&smB[(wc * 64 + tj * 16 + lcol) * 32 + q8];

#pragma unroll
        for (int ti = 0; ti < 4; ++ti)
#pragma unroll
            for (int tj = 0; tj < 4; ++tj)
                acc[ti][tj] = __builtin_amdgcn_mfma_f32_16x16x32_bf16(
                    av[ti], bv4[tj], acc[ti][tj], 0, 0, 0);
        __syncthreads();
    }

    // ---- epilogue ----
#pragma unroll
    for (int ti = 0; ti < 4; ++ti) {
        const long m0t = row0 + wr * 64 + ti * 16 + lrow;
#pragma unroll
        for (int tj = 0; tj < 4; ++tj) {
            const long n = col0 + wc * 64 + tj * 16 + lcol;
            const float bn = (biasp != nullptr) ? biasp[n] : 0.f;
            if (EPI == 0) {
                u16* C = (u16*)Cp + z * sC;
#pragma unroll
                for (int r = 0; r < 4; ++r)
                    C[(m0t + r) * ldc + n] = f2bf(acc[ti][tj][r] + bn);
            } else if (EPI == 1) {
                // v transposed: vT[b][n][ml], b from global m, ml = m & 2047
                u16* C = (u16*)Cp;
                const long b  = m0t >> 11;
                const long ml = m0t & 2047;
                ushort4 pk;
                pk.x = f2bf(acc[ti][tj][0] + bn);
                pk.y = f2bf(acc[ti][tj][1] + bn);
                pk.z = f2bf(acc[ti][tj][2] + bn);
                pk.w = f2bf(acc[ti][tj][3] + bn);
                *(ushort4*)&C[b * (512L * 2048) + n * 2048 + ml] = pk;
            } else {
                float* C = (float*)Cp;
#pragma unroll
                for (int r = 0; r < 4; ++r) {
                    const float val = acc[ti][tj][r] + bn;
                    C[(m0t + r) * ldc + n] = 1.0f / (1.0f + expf(-val));
                }
            }
        }
    }
}

// In-place bf16 row softmax over 2048 entries. 256 threads, 8 elems each.
__global__ __launch_bounds__(256) void softmax_bf(u16* __restrict__ S)
{
    u16* rowp = S + (long)blockIdx.x * APF_T;
    const int tid = threadIdx.x;

    const ushort4 ua = ((const ushort4*)rowp)[tid];
    const ushort4 ub = ((const ushort4*)rowp)[tid + 256];
    float a0 = bf2f(ua.x), a1 = bf2f(ua.y), a2 = bf2f(ua.z), a3 = bf2f(ua.w);
    float b0 = bf2f(ub.x), b1 = bf2f(ub.y), b2 = bf2f(ub.z), b3 = bf2f(ub.w);

    float mx = fmaxf(fmaxf(fmaxf(a0, a1), fmaxf(a2, a3)),
                     fmaxf(fmaxf(b0, b1), fmaxf(b2, b3)));
#pragma unroll
    for (int off = 32; off > 0; off >>= 1)
        mx = fmaxf(mx, __shfl_xor(mx, off));

    __shared__ float wm[4];
    __shared__ float wsum[4];
    const int wv = tid >> 6;
    const int ln = tid & 63;
    if (ln == 0) wm[wv] = mx;
    __syncthreads();
    mx = fmaxf(fmaxf(wm[0], wm[1]), fmaxf(wm[2], wm[3]));

    a0 = expf(a0 - mx); a1 = expf(a1 - mx); a2 = expf(a2 - mx); a3 = expf(a3 - mx);
    b0 = expf(b0 - mx); b1 = expf(b1 - mx); b2 = expf(b2 - mx); b3 = expf(b3 - mx);

    float sm = a0 + a1 + a2 + a3 + b0 + b1 + b2 + b3;
#pragma unroll
    for (int off = 32; off > 0; off >>= 1)
        sm += __shfl_xor(sm, off);
    if (ln == 0) wsum[wv] = sm;
    __syncthreads();
    sm = wsum[0] + wsum[1] + wsum[2] + wsum[3];

    const float inv = 1.0f / sm;
    ushort4 oa, ob;
    oa.x = f2bf(a0 * inv); oa.y = f2bf(a1 * inv);
    oa.z = f2bf(a2 * inv); oa.w = f2bf(a3 * inv);
    ob.x = f2bf(b0 * inv); ob.y = f2bf(b1 * inv);
    ob.z = f2bf(b2 * inv); ob.w = f2bf(b3 * inv);
    ((ushort4*)rowp)[tid]       = oa;
    ((ushort4*)rowp)[tid + 256] = ob;
}

extern "C" void kernel_launch(void* const* d_in, const int* in_sizes, int n_in,
                              void* d_out, int out_size, void* d_ws, size_t ws_size,
                              hipStream_t stream)
{
    (void)in_sizes; (void)n_in; (void)out_size; (void)ws_size;

    const float* x    = (const float*)d_in[0];  // [B,T,D]
    const float* pred = (const float*)d_in[1];  // [B,T,D]
    const float* Wq   = (const float*)d_in[2];  // [D,H]
    const float* bq   = (const float*)d_in[3];  // [H]
    const float* Wk   = (const float*)d_in[4];  // [D,H]
    const float* bk   = (const float*)d_in[5];  // [H]
    const float* Wv   = (const float*)d_in[6];  // [D,D]
    const float* bv   = (const float*)d_in[7];  // [D]
    const float* Wf   = (const float*)d_in[8];  // [2D,D]
    const float* bfu  = (const float*)d_in[9];  // [D]

    // Workspace (all u16 elements), ~144 MB total:
    u16* wsp   = (u16*)d_ws;
    u16* xb    = wsp;                                  // [16384][512]
    u16* predb = xb    + (long)APF_M * APF_D;          // [16384][512]
    u16* qb    = predb + (long)APF_M * APF_D;          // [16384][128]
    u16* kbuf  = qb    + (long)APF_M * APF_H;          // [16384][128]
    u16* vTb   = kbuf  + (long)APF_M * APF_H;          // [8][512][2048]
    u16* attb  = vTb   + (long)APF_M * APF_D;          // [16384][512]
    u16* WqT   = attb  + (long)APF_M * APF_D;          // [128][512]
    u16* WkT   = WqT   + (long)APF_H * APF_D;          // [128][512]
    u16* WvT   = WkT   + (long)APF_H * APF_D;          // [512][512]
    u16* WfT   = WvT   + (long)APF_D * APF_D;          // [512][1024]
    u16* scb   = WfT   + (long)APF_D * 2 * APF_D;      // [8][2048][2048] bf16

    const dim3 thr(256);
    const long nBTD4 = (long)APF_M * APF_D / 4;        // 2097152 float4s

    cvt_bf16<<<dim3(512), thr, 0, stream>>>(x,    xb,    nBTD4);
    cvt_bf16<<<dim3(512), thr, 0, stream>>>(pred, predb, nBTD4);
    tr_bf16<<<dim3((APF_D * APF_H + 255) / 256), thr, 0, stream>>>(Wq, WqT, APF_D, APF_H);
    tr_bf16<<<dim3((APF_D * APF_H + 255) / 256), thr, 0, stream>>>(Wk, WkT, APF_D, APF_H);
    tr_bf16<<<dim3((APF_D * APF_D + 255) / 256), thr, 0, stream>>>(Wv, WvT, APF_D, APF_D);
    tr_bf16<<<dim3((2 * APF_D * APF_D + 255) / 256), thr, 0, stream>>>(Wf, WfT, 2 * APF_D, APF_D);

    // q = pred @ Wq + bq -> bf16 [16384][128]
    mfma_gemm<0, 0><<<dim3(1, 128, 1), thr, 0, stream>>>(
        predb, nullptr, APF_D, WqT, APF_D, bq, qb, APF_H, APF_D, 0, 0, 0);
    // k = x @ Wk + bk -> bf16 [16384][128]
    mfma_gemm<0, 0><<<dim3(1, 128, 1), thr, 0, stream>>>(
        xb, nullptr, APF_D, WkT, APF_D, bk, kbuf, APF_H, APF_D, 0, 0, 0);
    // v = x @ Wv + bv -> bf16 TRANSPOSED vT[8][512][2048]
    mfma_gemm<0, 1><<<dim3(4, 128, 1), thr, 0, stream>>>(
        xb, nullptr, APF_D, WvT, APF_D, bv, vTb, 0, APF_D, 0, 0, 0);

    // scores[z] = q[z] @ k[z]^T -> bf16 [2048][2048] per batch
    mfma_gemm<0, 0><<<dim3(16, 16, 8), thr, 0, stream>>>(
        qb, nullptr, APF_H, kbuf, APF_H, nullptr, scb, APF_T, APF_H,
        (long)APF_T * APF_H, (long)APF_T * APF_H, (long)APF_T * APF_T);

    // softmax in place (16384 rows)
    softmax_bf<<<dim3(APF_M), thr, 0, stream>>>(scb);

    // att[z] = P[z] @ v[z] -> bf16 [2048][512] per batch (contiguous [16384][512])
    mfma_gemm<0, 0><<<dim3(4, 16, 8), thr, 0, stream>>>(
        scb, nullptr, APF_T, vTb, APF_T, nullptr, attb, APF_D, APF_T,
        (long)APF_T * APF_T, (long)APF_D * APF_T, (long)APF_T * APF_D);

    // out = sigmoid([pred|att] @ Wf + bf) -> fp32 d_out [16384][512]
    mfma_gemm<1, 2><<<dim3(4, 128, 1), thr, 0, stream>>>(
        predb, attb, APF_D, WfT, 2 * APF_D, bfu, d_out, APF_D, 2 * APF_D, 0, 0, 0);
}

// Round 6
// 306.726 us; speedup vs baseline: 3.6980x; 1.1647x over previous
//
#include <hip/hip_runtime.h>
#include <hip/hip_bf16.h>

// AttentivePredictionFusion: B=8, T=2048, D=512, H=128. fp32 in, fp32 out.
// R6: (1) global_load_lds width-16 async staging in all MFMA GEMMs;
//     (2) softmax kernel eliminated: QK^T epilogue stores exp(S) bf16 +
//         atomic row sums; PV epilogue scales by 1/rowsum (softmax commutes
//         with the V matmul; |scores|<~25 so exp is fp32-safe w/o max-sub);
//     (3) q&k GEMMs merged into one z-batched dispatch; prep fused to 2 kernels.

#define APF_B 8
#define APF_T 2048
#define APF_D 512
#define APF_H 128
#define APF_M (APF_B * APF_T)   // 16384

typedef unsigned short u16;
typedef __attribute__((ext_vector_type(8))) short short8;
typedef __attribute__((ext_vector_type(4))) float f32x4;

static __device__ __forceinline__ float bf2f(u16 u) {
    union { unsigned int i; float f; } w;
    w.i = ((unsigned int)u) << 16;
    return w.f;
}
static __device__ __forceinline__ u16 f2bf(float x) {
    union { float f; unsigned int u; } cv;
    cv.f = x;
    unsigned int u = cv.u + 0x7FFFu + ((cv.u >> 16) & 1u);  // RNE
    return (u16)(u >> 16);
}

// async global->LDS, 16 B per lane; LDS dest = wave-uniform base + lane*16
static __device__ __forceinline__ void load16_lds(const u16* g, u16* l) {
    __builtin_amdgcn_global_load_lds(
        (const __attribute__((address_space(1))) unsigned int*)g,
        (__attribute__((address_space(3))) unsigned int*)l,
        16, 0, 0);
}

// ---------------- prep kernels ----------------

// fp32 -> bf16 for x and pred in one launch. n4 = float4 count per tensor.
__global__ __launch_bounds__(256) void cvt_pair(const float* __restrict__ in0,
                                                u16* __restrict__ out0,
                                                const float* __restrict__ in1,
                                                u16* __restrict__ out1, long n4)
{
    long i = blockIdx.x * 256L + threadIdx.x;
    const long stride = (long)gridDim.x * 256L;
    for (; i < 2 * n4; i += stride) {
        const float* in = (i < n4) ? in0 : in1;
        u16* out = (i < n4) ? out0 : out1;
        const long j = (i < n4) ? i : (i - n4);
        const float4 v = ((const float4*)in)[j];
        ushort4 o;
        o.x = f2bf(v.x); o.y = f2bf(v.y); o.z = f2bf(v.z); o.w = f2bf(v.w);
        ((ushort4*)out)[j] = o;
    }
}

// all 4 weight transposes (fp32 [K][N] -> bf16 [N][K]) + rowsum zeroing.
__global__ __launch_bounds__(256) void prep_weights(
    const float* __restrict__ Wq, u16* __restrict__ WqT,
    const float* __restrict__ Wk, u16* __restrict__ WkT,
    const float* __restrict__ Wv, u16* __restrict__ WvT,
    const float* __restrict__ Wf, u16* __restrict__ WfT,
    float* __restrict__ rowsum)
{
    const long e = blockIdx.x * 256L + threadIdx.x;
    // segment sizes: 65536, 65536, 262144, 524288, 16384
    if (e < 65536) {
        const long idx = e;              // Wq: K=512,N=128
        const long n = idx / 512, k = idx % 512;
        WqT[idx] = f2bf(Wq[k * 128 + n]);
    } else if (e < 131072) {
        const long idx = e - 65536;      // Wk: K=512,N=128
        const long n = idx / 512, k = idx % 512;
        WkT[idx] = f2bf(Wk[k * 128 + n]);
    } else if (e < 393216) {
        const long idx = e - 131072;     // Wv: K=512,N=512
        const long n = idx / 512, k = idx % 512;
        WvT[idx] = f2bf(Wv[k * 512 + n]);
    } else if (e < 917504) {
        const long idx = e - 393216;     // Wf: K=1024,N=512
        const long n = idx / 1024, k = idx % 1024;
        WfT[idx] = f2bf(Wf[k * 512 + n]);
    } else if (e < 933888) {
        rowsum[e - 917504] = 0.0f;
    }
}

// ---------------- MFMA GEMM ----------------
// A: bf16 [M][K] row-major; B: bf16 [N][K] row-major (K-contiguous).
// DUAL: 0 = plain batched (z strides sA/sB/sC)
//       1 = concat A (k<512 from Ap, else A2p at col-512), single batch
//       2 = z-select: z==0 -> (Ap,Bp,biasp,Cp); z==1 -> (A2p,Bp2,bias2,Cp2)
// EPI:  0 = bf16 store +bias
//       1 = bf16 transposed store vT[b][n][ml] +bias
//       2 = fp32 sigmoid store +bias
//       3 = exp() bf16 store + atomicAdd row sums into rowsum[z*T + m]
//       4 = scale by 1/rowsum[z*T + m], bf16 store
// Tile 128x128, BK=32, 256 threads = 4 waves (2x2), each wave 4x4 MFMA 16x16x32.
template <int DUAL, int EPI>
__global__ __launch_bounds__(256) void mfma_gemm(
    const u16* __restrict__ Ap, const u16* __restrict__ A2p, long lda,
    const u16* __restrict__ Bp, const u16* __restrict__ Bp2, long ldb,
    const float* __restrict__ biasp, const float* __restrict__ bias2,
    void* __restrict__ Cp, void* __restrict__ Cp2, long ldc, int K,
    long sA, long sB, long sC, float* __restrict__ rowsum)
{
    __shared__ u16 smA[128 * 32];
    __shared__ u16 smB[128 * 32];

    const int tid  = threadIdx.x;
    const int lane = tid & 63;
    const int wid  = tid >> 6;
    const int wr   = wid >> 1;
    const int wc   = wid & 1;

    const long row0 = (long)blockIdx.y * 128;
    const long col0 = (long)blockIdx.x * 128;
    const long z    = blockIdx.z;

    const u16* Abase = (DUAL == 2) ? (z ? A2p : Ap) : (Ap + z * sA);
    const u16* Bbase = (DUAL == 2) ? (z ? Bp2 : Bp) : (Bp + z * sB);

    f32x4 acc[4][4];
#pragma unroll
    for (int i = 0; i < 4; ++i)
#pragma unroll
        for (int j = 0; j < 4; ++j)
            acc[i][j] = (f32x4){0.f, 0.f, 0.f, 0.f};

    const int lrow = (lane >> 4) * 4;
    const int lcol = lane & 15;
    const int q8   = (lane >> 4) * 8;

    for (int kb = 0; kb < K; kb += 32) {
        // async stage A,B tiles [128][32] bf16; chunk c -> LDS offset c*16B
#pragma unroll
        for (int rep = 0; rep < 2; ++rep) {
            const int c  = tid + rep * 256;
            const int r  = c >> 2;
            const int kc = (c & 3) * 8;
            const int wbase = (wid * 64 + rep * 256) * 8;  // u16 units (lane<<3 implicit)
            const u16* ga;
            if (DUAL == 1 && (kb + kc) >= APF_D) {
                ga = A2p + (row0 + r) * lda + (kb + kc - APF_D);
            } else {
                ga = Abase + (row0 + r) * lda + (kb + kc);
            }
            load16_lds(ga, &smA[wbase]);
            const u16* gb = Bbase + (col0 + r) * ldb + (kb + kc);
            load16_lds(gb, &smB[wbase]);
        }
        __syncthreads();

        short8 av[4], bv4[4];
#pragma unroll
        for (int ti = 0; ti < 4; ++ti)
            av[ti] = *(const short8*)&smA[(wr * 64 + ti * 16 + lcol) * 32 + q8];
#pragma unroll
        for (int tj = 0; tj < 4; ++tj)
            bv4[tj] = *(const short8*)&smB[(wc * 64 + tj * 16 + lcol) * 32 + q8];

#pragma unroll
        for (int ti = 0; ti < 4; ++ti)
#pragma unroll
            for (int tj = 0; tj < 4; ++tj)
                acc[ti][tj] = __builtin_amdgcn_mfma_f32_16x16x32_bf16(
                    av[ti], bv4[tj], acc[ti][tj], 0, 0, 0);
        __syncthreads();
    }

    const float* bias = (DUAL == 2 && z) ? bias2 : biasp;

    // ---- epilogue ----
#pragma unroll
    for (int ti = 0; ti < 4; ++ti) {
        const long m0t = row0 + wr * 64 + ti * 16 + lrow;
#pragma unroll
        for (int tj = 0; tj < 4; ++tj) {
            const long n = col0 + wc * 64 + tj * 16 + lcol;
            if (EPI == 0) {
                const float bn = (bias != nullptr) ? bias[n] : 0.f;
                u16* C = (u16*)((DUAL == 2 && z) ? Cp2 : Cp) + ((DUAL == 2) ? 0 : z * sC);
#pragma unroll
                for (int r = 0; r < 4; ++r)
                    C[(m0t + r) * ldc + n] = f2bf(acc[ti][tj][r] + bn);
            } else if (EPI == 1) {
                const float bn = (bias != nullptr) ? bias[n] : 0.f;
                u16* C = (u16*)Cp;
                const long b  = m0t >> 11;
                const long ml = m0t & 2047;
                ushort4 pk;
                pk.x = f2bf(acc[ti][tj][0] + bn);
                pk.y = f2bf(acc[ti][tj][1] + bn);
                pk.z = f2bf(acc[ti][tj][2] + bn);
                pk.w = f2bf(acc[ti][tj][3] + bn);
                *(ushort4*)&C[b * (512L * 2048) + n * 2048 + ml] = pk;
            } else if (EPI == 2) {
                const float bn = (bias != nullptr) ? bias[n] : 0.f;
                float* C = (float*)Cp;
#pragma unroll
                for (int r = 0; r < 4; ++r) {
                    const float val = acc[ti][tj][r] + bn;
                    C[(m0t + r) * ldc + n] = 1.0f / (1.0f + expf(-val));
                }
            } else if (EPI == 3) {
                u16* C = (u16*)Cp + z * sC;
#pragma unroll
                for (int r = 0; r < 4; ++r) {
                    const float e = __expf(acc[ti][tj][r]);
                    acc[ti][tj][r] = e;           // keep for row sums
                    C[(m0t + r) * ldc + n] = f2bf(e);
                }
            } else {  // EPI == 4
                u16* C = (u16*)Cp + z * sC;
#pragma unroll
                for (int r = 0; r < 4; ++r) {
                    const float inv = 1.0f / rowsum[z * APF_T + m0t + r];
                    C[(m0t + r) * ldc + n] = f2bf(acc[ti][tj][r] * inv);
                }
            }
        }
    }

    if (EPI == 3) {
        // per-row partial sums: sum over tj and over the 16 lanes of each row group
#pragma unroll
        for (int ti = 0; ti < 4; ++ti) {
            const long m0t = row0 + wr * 64 + ti * 16 + lrow;
#pragma unroll
            for (int r = 0; r < 4; ++r) {
                float s = acc[ti][0][r] + acc[ti][1][r] + acc[ti][2][r] + acc[ti][3][r];
                s += __shfl_xor(s, 1);
                s += __shfl_xor(s, 2);
                s += __shfl_xor(s, 4);
                s += __shfl_xor(s, 8);
                if (lcol == 0)
                    atomicAdd(&rowsum[z * APF_T + m0t + r], s);
            }
        }
    }
}

extern "C" void kernel_launch(void* const* d_in, const int* in_sizes, int n_in,
                              void* d_out, int out_size, void* d_ws, size_t ws_size,
                              hipStream_t stream)
{
    (void)in_sizes; (void)n_in; (void)out_size; (void)ws_size;

    const float* x    = (const float*)d_in[0];
    const float* pred = (const float*)d_in[1];
    const float* Wq   = (const float*)d_in[2];
    const float* bq   = (const float*)d_in[3];
    const float* Wk   = (const float*)d_in[4];
    const float* bk   = (const float*)d_in[5];
    const float* Wv   = (const float*)d_in[6];
    const float* bv   = (const float*)d_in[7];
    const float* Wf   = (const float*)d_in[8];
    const float* bfu  = (const float*)d_in[9];

    // Workspace (u16 unless noted), ~138 MB:
    u16* wsp   = (u16*)d_ws;
    u16* xb    = wsp;                                  // [16384][512]
    u16* predb = xb    + (long)APF_M * APF_D;          // [16384][512]
    u16* qb    = predb + (long)APF_M * APF_D;          // [16384][128]
    u16* kbuf  = qb    + (long)APF_M * APF_H;          // [16384][128]
    u16* vTb   = kbuf  + (long)APF_M * APF_H;          // [8][512][2048]
    u16* attb  = vTb   + (long)APF_M * APF_D;          // [16384][512]
    u16* WqT   = attb  + (long)APF_M * APF_D;          // [128][512]
    u16* WkT   = WqT   + (long)APF_H * APF_D;          // [128][512]
    u16* WvT   = WkT   + (long)APF_H * APF_D;          // [512][512]
    u16* WfT   = WvT   + (long)APF_D * APF_D;          // [512][1024]
    float* rsum = (float*)(WfT + (long)APF_D * 2 * APF_D);  // [16384] f32
    u16* scb   = (u16*)(rsum + APF_M);                 // [8][2048][2048] exp(S) bf16

    const dim3 thr(256);
    const long nBTD4 = (long)APF_M * APF_D / 4;

    cvt_pair<<<dim3(1024), thr, 0, stream>>>(x, xb, pred, predb, nBTD4);
    prep_weights<<<dim3(3648), thr, 0, stream>>>(Wq, WqT, Wk, WkT, Wv, WvT, Wf, WfT, rsum);

    // q = pred@Wq+bq (z=0), k = x@Wk+bk (z=1), merged
    mfma_gemm<2, 0><<<dim3(1, 128, 2), thr, 0, stream>>>(
        predb, xb, APF_D, WqT, WkT, APF_D, bq, bk, qb, kbuf, APF_H, APF_D,
        0, 0, 0, nullptr);

    // v = x @ Wv + bv -> transposed vT[8][512][2048]
    mfma_gemm<0, 1><<<dim3(4, 128, 1), thr, 0, stream>>>(
        xb, nullptr, APF_D, WvT, nullptr, APF_D, bv, nullptr, vTb, nullptr,
        0, APF_D, 0, 0, 0, nullptr);

    // Punorm[z] = exp(q[z] @ k[z]^T) bf16 + row sums
    mfma_gemm<0, 3><<<dim3(16, 16, 8), thr, 0, stream>>>(
        qb, nullptr, APF_H, kbuf, nullptr, APF_H, nullptr, nullptr, scb, nullptr,
        APF_T, APF_H, (long)APF_T * APF_H, (long)APF_T * APF_H,
        (long)APF_T * APF_T, rsum);

    // att[z] = (Punorm[z] @ v[z]) / rowsum -> bf16 [16384][512]
    mfma_gemm<0, 4><<<dim3(4, 16, 8), thr, 0, stream>>>(
        scb, nullptr, APF_T, vTb, nullptr, APF_T, nullptr, nullptr, attb, nullptr,
        APF_D, APF_T, (long)APF_T * APF_T, (long)APF_D * APF_T,
        (long)APF_T * APF_D, rsum);

    // out = sigmoid([pred|att] @ Wf + bf) -> fp32 d_out
    mfma_gemm<1, 2><<<dim3(4, 128, 1), thr, 0, stream>>>(
        predb, attb, APF_D, WfT, nullptr, 2 * APF_D, bfu, nullptr, d_out, nullptr,
        APF_D, 2 * APF_D, 0, 0, 0, nullptr);
}

// Round 7
// 297.262 us; speedup vs baseline: 3.8157x; 1.0318x over previous
//
#include <hip/hip_runtime.h>
#include <hip/hip_bf16.h>

// AttentivePredictionFusion: B=8, T=2048, D=512, H=128. fp32 in, fp32 out.
// R7: flash-style fused attention (QK^T + exp + PV + end normalization) in one
// kernel -- no scores materialization, no atomics, no online rescaling (|S|<~25
// so exp is fp32-safe; validated R6). GEMMs for q/k, v(->vT), fusion unchanged
// (m97-style global_load_lds staging).

#define APF_B 8
#define APF_T 2048
#define APF_D 512
#define APF_H 128
#define APF_M (APF_B * APF_T)   // 16384

typedef unsigned short u16;
typedef __attribute__((ext_vector_type(8))) short short8;
typedef __attribute__((ext_vector_type(4))) float f32x4;

static __device__ __forceinline__ float bf2f(u16 u) {
    union { unsigned int i; float f; } w;
    w.i = ((unsigned int)u) << 16;
    return w.f;
}
static __device__ __forceinline__ u16 f2bf(float x) {
    union { float f; unsigned int u; } cv;
    cv.f = x;
    unsigned int u = cv.u + 0x7FFFu + ((cv.u >> 16) & 1u);  // RNE
    return (u16)(u >> 16);
}

// async global->LDS, 16 B per lane; LDS dest = wave-uniform base + lane*16
static __device__ __forceinline__ void load16_lds(const u16* g, u16* l) {
    __builtin_amdgcn_global_load_lds(
        (const __attribute__((address_space(1))) unsigned int*)g,
        (__attribute__((address_space(3))) unsigned int*)l,
        16, 0, 0);
}

// ---------------- prep kernels ----------------

__global__ __launch_bounds__(256) void cvt_pair(const float* __restrict__ in0,
                                                u16* __restrict__ out0,
                                                const float* __restrict__ in1,
                                                u16* __restrict__ out1, long n4)
{
    long i = blockIdx.x * 256L + threadIdx.x;
    const long stride = (long)gridDim.x * 256L;
    for (; i < 2 * n4; i += stride) {
        const float* in = (i < n4) ? in0 : in1;
        u16* out = (i < n4) ? out0 : out1;
        const long j = (i < n4) ? i : (i - n4);
        const float4 v = ((const float4*)in)[j];
        ushort4 o;
        o.x = f2bf(v.x); o.y = f2bf(v.y); o.z = f2bf(v.z); o.w = f2bf(v.w);
        ((ushort4*)out)[j] = o;
    }
}

// weight transposes (fp32 [K][N] -> bf16 [N][K])
__global__ __launch_bounds__(256) void prep_weights(
    const float* __restrict__ Wq, u16* __restrict__ WqT,
    const float* __restrict__ Wk, u16* __restrict__ WkT,
    const float* __restrict__ Wv, u16* __restrict__ WvT,
    const float* __restrict__ Wf, u16* __restrict__ WfT)
{
    const long e = blockIdx.x * 256L + threadIdx.x;
    if (e < 65536) {
        const long idx = e;              // Wq: K=512,N=128
        const long n = idx / 512, k = idx % 512;
        WqT[idx] = f2bf(Wq[k * 128 + n]);
    } else if (e < 131072) {
        const long idx = e - 65536;      // Wk
        const long n = idx / 512, k = idx % 512;
        WkT[idx] = f2bf(Wk[k * 128 + n]);
    } else if (e < 393216) {
        const long idx = e - 131072;     // Wv: K=512,N=512
        const long n = idx / 512, k = idx % 512;
        WvT[idx] = f2bf(Wv[k * 512 + n]);
    } else if (e < 917504) {
        const long idx = e - 393216;     // Wf: K=1024,N=512
        const long n = idx / 1024, k = idx % 1024;
        WfT[idx] = f2bf(Wf[k * 512 + n]);
    }
}

// ---------------- MFMA GEMM (projections / fusion) ----------------
// A: bf16 [M][K]; B: bf16 [N][K]. DUAL: 0 plain batched; 1 concat-A; 2 z-select.
// EPI: 0 bf16 store +bias; 1 bf16 transposed store vT[b][n][ml] +bias;
//      2 fp32 sigmoid store +bias.
template <int DUAL, int EPI>
__global__ __launch_bounds__(256) void mfma_gemm(
    const u16* __restrict__ Ap, const u16* __restrict__ A2p, long lda,
    const u16* __restrict__ Bp, const u16* __restrict__ Bp2, long ldb,
    const float* __restrict__ biasp, const float* __restrict__ bias2,
    void* __restrict__ Cp, void* __restrict__ Cp2, long ldc, int K,
    long sA, long sB, long sC)
{
    __shared__ u16 smA[128 * 32];
    __shared__ u16 smB[128 * 32];

    const int tid  = threadIdx.x;
    const int lane = tid & 63;
    const int wid  = tid >> 6;
    const int wr   = wid >> 1;
    const int wc   = wid & 1;

    const long row0 = (long)blockIdx.y * 128;
    const long col0 = (long)blockIdx.x * 128;
    const long z    = blockIdx.z;

    const u16* Abase = (DUAL == 2) ? (z ? A2p : Ap) : (Ap + z * sA);
    const u16* Bbase = (DUAL == 2) ? (z ? Bp2 : Bp) : (Bp + z * sB);

    f32x4 acc[4][4];
#pragma unroll
    for (int i = 0; i < 4; ++i)
#pragma unroll
        for (int j = 0; j < 4; ++j)
            acc[i][j] = (f32x4){0.f, 0.f, 0.f, 0.f};

    const int lrow = (lane >> 4) * 4;
    const int lcol = lane & 15;
    const int q8   = (lane >> 4) * 8;

    for (int kb = 0; kb < K; kb += 32) {
#pragma unroll
        for (int rep = 0; rep < 2; ++rep) {
            const int c  = tid + rep * 256;
            const int r  = c >> 2;
            const int kc = (c & 3) * 8;
            const int wbase = (wid * 64 + rep * 256) * 8;
            const u16* ga;
            if (DUAL == 1 && (kb + kc) >= APF_D) {
                ga = A2p + (row0 + r) * lda + (kb + kc - APF_D);
            } else {
                ga = Abase + (row0 + r) * lda + (kb + kc);
            }
            load16_lds(ga, &smA[wbase]);
            const u16* gb = Bbase + (col0 + r) * ldb + (kb + kc);
            load16_lds(gb, &smB[wbase]);
        }
        __syncthreads();

        short8 av[4], bv4[4];
#pragma unroll
        for (int ti = 0; ti < 4; ++ti)
            av[ti] = *(const short8*)&smA[(wr * 64 + ti * 16 + lcol) * 32 + q8];
#pragma unroll
        for (int tj = 0; tj < 4; ++tj)
            bv4[tj] = *(const short8*)&smB[(wc * 64 + tj * 16 + lcol) * 32 + q8];

#pragma unroll
        for (int ti = 0; ti < 4; ++ti)
#pragma unroll
            for (int tj = 0; tj < 4; ++tj)
                acc[ti][tj] = __builtin_amdgcn_mfma_f32_16x16x32_bf16(
                    av[ti], bv4[tj], acc[ti][tj], 0, 0, 0);
        __syncthreads();
    }

    const float* bias = (DUAL == 2 && z) ? bias2 : biasp;

#pragma unroll
    for (int ti = 0; ti < 4; ++ti) {
        const long m0t = row0 + wr * 64 + ti * 16 + lrow;
#pragma unroll
        for (int tj = 0; tj < 4; ++tj) {
            const long n = col0 + wc * 64 + tj * 16 + lcol;
            const float bn = (bias != nullptr) ? bias[n] : 0.f;
            if (EPI == 0) {
                u16* C = (u16*)((DUAL == 2 && z) ? Cp2 : Cp) + ((DUAL == 2) ? 0 : z * sC);
#pragma unroll
                for (int r = 0; r < 4; ++r)
                    C[(m0t + r) * ldc + n] = f2bf(acc[ti][tj][r] + bn);
            } else if (EPI == 1) {
                u16* C = (u16*)Cp;
                const long b  = m0t >> 11;
                const long ml = m0t & 2047;
                ushort4 pk;
                pk.x = f2bf(acc[ti][tj][0] + bn);
                pk.y = f2bf(acc[ti][tj][1] + bn);
                pk.z = f2bf(acc[ti][tj][2] + bn);
                pk.w = f2bf(acc[ti][tj][3] + bn);
                *(ushort4*)&C[b * (512L * 2048) + n * 2048 + ml] = pk;
            } else {
                float* C = (float*)Cp;
#pragma unroll
                for (int r = 0; r < 4; ++r) {
                    const float val = acc[ti][tj][r] + bn;
                    C[(m0t + r) * ldc + n] = 1.0f / (1.0f + expf(-val));
                }
            }
        }
    }
}

// ---------------- fused attention ----------------
// Grid (D-chunks=2, Q-tiles=16, B=8); 512 threads = 8 waves.
// Block: Q rows [q0,q0+128), out cols [d0,d0+256). Wave w owns Q rows
// [q0+16w, +16). Loop s-tiles of 64: S = Q@K^T (MFMA), P = exp(S) -> LDS
// (C->A layout hop), O += P@V (MFMA), rowsum accumulated in registers.
// End: butterfly-reduce rowsum over the 16 col-lanes, scale, bf16 store.
// LDS rows padded (+8 u16) so frag reads are 2-way-bank-aliased (free, m136).
#define FA_LDQ 136
#define FA_LDK 136
#define FA_LDV 72
#define FA_LDP 72

__global__ __launch_bounds__(512, 2) void attn_fused(
    const u16* __restrict__ qg, const u16* __restrict__ kg,
    const u16* __restrict__ vTg, u16* __restrict__ attg)
{
    __shared__ u16 sQ[128 * FA_LDQ];
    __shared__ u16 sK[64 * FA_LDK];
    __shared__ u16 sV[256 * FA_LDV];
    __shared__ u16 sP[128 * FA_LDP];

    const int tid  = threadIdx.x;
    const int lane = tid & 63;
    const int w    = tid >> 6;       // 0..7
    const int l15  = lane & 15;
    const int q4   = lane >> 4;      // 0..3

    const long z  = blockIdx.z;
    const long q0 = (long)blockIdx.y * 128;
    const long d0 = (long)blockIdx.x * 256;

    // stage Q tile once (contiguous 128x128 u16)
    {
        const u16* src = qg + (z * APF_T + q0) * APF_H;
#pragma unroll
        for (int rep = 0; rep < 4; ++rep) {
            const int c   = tid + rep * 512;      // 0..2047
            const int row = c >> 4;
            const int c8  = (c & 15) * 8;
            *(uint4*)&sQ[row * FA_LDQ + c8] = *(const uint4*)(src + (long)c * 8);
        }
    }

    f32x4 oacc[16];
#pragma unroll
    for (int i = 0; i < 16; ++i) oacc[i] = (f32x4){0.f, 0.f, 0.f, 0.f};
    float rs[4] = {0.f, 0.f, 0.f, 0.f};

    for (int kt = 0; kt < APF_T / 64; ++kt) {
        __syncthreads();   // prev iter's sK/sV reads done (also covers sQ stage)
        // stage K tile (contiguous 64x128 u16)
        {
            const u16* src = kg + (z * APF_T + (long)kt * 64) * APF_H;
#pragma unroll
            for (int rep = 0; rep < 2; ++rep) {
                const int c   = tid + rep * 512;  // 0..1023
                const int row = c >> 4;
                const int c8  = (c & 15) * 8;
                *(uint4*)&sK[row * FA_LDK + c8] = *(const uint4*)(src + (long)c * 8);
            }
        }
        // stage V tile: sV[d][s] from vT[z][d0+d][kt*64+s]
        {
            const u16* src = vTg + z * ((long)APF_D * APF_T) + d0 * APF_T + (long)kt * 64;
#pragma unroll
            for (int rep = 0; rep < 4; ++rep) {
                const int c   = tid + rep * 512;  // 0..2047
                const int row = c >> 3;           // 0..255
                const int c8  = (c & 7) * 8;      // 0..56
                *(uint4*)&sV[row * FA_LDV + c8] =
                    *(const uint4*)(src + (long)row * APF_T + c8);
            }
        }
        __syncthreads();

        // S(16x64 per wave) = Q_w @ K_tile^T, contraction over h=128
        f32x4 sacc[4];
#pragma unroll
        for (int tj = 0; tj < 4; ++tj) sacc[tj] = (f32x4){0.f, 0.f, 0.f, 0.f};
#pragma unroll
        for (int kk = 0; kk < 4; ++kk) {
            const short8 av = *(const short8*)&sQ[(w * 16 + l15) * FA_LDQ + kk * 32 + q4 * 8];
#pragma unroll
            for (int tj = 0; tj < 4; ++tj) {
                const short8 bv = *(const short8*)&sK[(tj * 16 + l15) * FA_LDK + kk * 32 + q4 * 8];
                sacc[tj] = __builtin_amdgcn_mfma_f32_16x16x32_bf16(av, bv, sacc[tj], 0, 0, 0);
            }
        }
        // exp + rowsum + P to LDS (C-layout -> A-layout hop)
#pragma unroll
        for (int tj = 0; tj < 4; ++tj)
#pragma unroll
            for (int r = 0; r < 4; ++r) {
                const float e = __expf(sacc[tj][r]);
                rs[r] += e;
                sP[(w * 16 + q4 * 4 + r) * FA_LDP + tj * 16 + l15] = f2bf(e);
            }
        // O(16x256 per wave) += P_w(16x64) @ V(256x64)^T  (wave-local sP rows)
#pragma unroll
        for (int kk = 0; kk < 2; ++kk) {
            const short8 ap = *(const short8*)&sP[(w * 16 + l15) * FA_LDP + kk * 32 + q4 * 8];
#pragma unroll
            for (int dt = 0; dt < 16; ++dt) {
                const short8 bv = *(const short8*)&sV[(dt * 16 + l15) * FA_LDV + kk * 32 + q4 * 8];
                oacc[dt] = __builtin_amdgcn_mfma_f32_16x16x32_bf16(ap, bv, oacc[dt], 0, 0, 0);
            }
        }
    }

    // rowsum reduce across the 16 col-lanes (bits 0..3 of lane)
#pragma unroll
    for (int r = 0; r < 4; ++r) {
        float s = rs[r];
        s += __shfl_xor(s, 1);
        s += __shfl_xor(s, 2);
        s += __shfl_xor(s, 4);
        s += __shfl_xor(s, 8);
        rs[r] = 1.0f / s;
    }

    // store att rows
    const long mbase = z * APF_T + q0 + w * 16 + q4 * 4;
#pragma unroll
    for (int dt = 0; dt < 16; ++dt) {
        const long col = d0 + dt * 16 + l15;
#pragma unroll
        for (int r = 0; r < 4; ++r)
            attg[(mbase + r) * APF_D + col] = f2bf(oacc[dt][r] * rs[r]);
    }
}

extern "C" void kernel_launch(void* const* d_in, const int* in_sizes, int n_in,
                              void* d_out, int out_size, void* d_ws, size_t ws_size,
                              hipStream_t stream)
{
    (void)in_sizes; (void)n_in; (void)out_size; (void)ws_size;

    const float* x    = (const float*)d_in[0];
    const float* pred = (const float*)d_in[1];
    const float* Wq   = (const float*)d_in[2];
    const float* bq   = (const float*)d_in[3];
    const float* Wk   = (const float*)d_in[4];
    const float* bk   = (const float*)d_in[5];
    const float* Wv   = (const float*)d_in[6];
    const float* bv   = (const float*)d_in[7];
    const float* Wf   = (const float*)d_in[8];
    const float* bfu  = (const float*)d_in[9];

    // Workspace (u16), ~80 MB
    u16* wsp   = (u16*)d_ws;
    u16* xb    = wsp;                                  // [16384][512]
    u16* predb = xb    + (long)APF_M * APF_D;          // [16384][512]
    u16* qb    = predb + (long)APF_M * APF_D;          // [16384][128]
    u16* kbuf  = qb    + (long)APF_M * APF_H;          // [16384][128]
    u16* vTb   = kbuf  + (long)APF_M * APF_H;          // [8][512][2048]
    u16* attb  = vTb   + (long)APF_M * APF_D;          // [16384][512]
    u16* WqT   = attb  + (long)APF_M * APF_D;          // [128][512]
    u16* WkT   = WqT   + (long)APF_H * APF_D;          // [128][512]
    u16* WvT   = WkT   + (long)APF_H * APF_D;          // [512][512]
    u16* WfT   = WvT   + (long)APF_D * APF_D;          // [512][1024]

    const dim3 thr(256);
    const long nBTD4 = (long)APF_M * APF_D / 4;

    cvt_pair<<<dim3(1024), thr, 0, stream>>>(x, xb, pred, predb, nBTD4);
    prep_weights<<<dim3(3584), thr, 0, stream>>>(Wq, WqT, Wk, WkT, Wv, WvT, Wf, WfT);

    // q = pred@Wq+bq (z=0), k = x@Wk+bk (z=1)
    mfma_gemm<2, 0><<<dim3(1, 128, 2), thr, 0, stream>>>(
        predb, xb, APF_D, WqT, WkT, APF_D, bq, bk, qb, kbuf, APF_H, APF_D,
        0, 0, 0);

    // v = x @ Wv + bv -> transposed vT[8][512][2048]
    mfma_gemm<0, 1><<<dim3(4, 128, 1), thr, 0, stream>>>(
        xb, nullptr, APF_D, WvT, nullptr, APF_D, bv, nullptr, vTb, nullptr,
        0, APF_D, 0, 0, 0);

    // fused attention: att = softmax(q k^T) v   (one kernel, no scores buffer)
    attn_fused<<<dim3(2, 16, 8), dim3(512), 0, stream>>>(qb, kbuf, vTb, attb);

    // out = sigmoid([pred|att] @ Wf + bf) -> fp32 d_out
    mfma_gemm<1, 2><<<dim3(4, 128, 1), thr, 0, stream>>>(
        predb, attb, APF_D, WfT, nullptr, 2 * APF_D, bfu, nullptr, d_out, nullptr,
        APF_D, 2 * APF_D, 0, 0, 0);
}

// Round 8
// 290.951 us; speedup vs baseline: 3.8985x; 1.0217x over previous
//
#include <hip/hip_runtime.h>
#include <hip/hip_bf16.h>

// AttentivePredictionFusion: B=8, T=2048, D=512, H=128. fp32 in, fp32 out.
// R8: (1) attn_fused reshaped to 256thr/4waves, Q-tile 64, LDS 79KB ->
//     2 blocks/CU (R7 was 105KB -> 1 block/CU, lockstep-serialized chain);
//     (2) vT produced by operand swap (A=WvT, B=x) -> coalesced stores,
//     replacing the 4KB-stride ushort4 scatter epilogue.

#define APF_B 8
#define APF_T 2048
#define APF_D 512
#define APF_H 128
#define APF_M (APF_B * APF_T)   // 16384

typedef unsigned short u16;
typedef __attribute__((ext_vector_type(8))) short short8;
typedef __attribute__((ext_vector_type(4))) float f32x4;

static __device__ __forceinline__ float bf2f(u16 u) {
    union { unsigned int i; float f; } w;
    w.i = ((unsigned int)u) << 16;
    return w.f;
}
static __device__ __forceinline__ u16 f2bf(float x) {
    union { float f; unsigned int u; } cv;
    cv.f = x;
    unsigned int u = cv.u + 0x7FFFu + ((cv.u >> 16) & 1u);  // RNE
    return (u16)(u >> 16);
}

// async global->LDS, 16 B per lane; LDS dest = wave-uniform base + lane*16
static __device__ __forceinline__ void load16_lds(const u16* g, u16* l) {
    __builtin_amdgcn_global_load_lds(
        (const __attribute__((address_space(1))) unsigned int*)g,
        (__attribute__((address_space(3))) unsigned int*)l,
        16, 0, 0);
}

// ---------------- prep kernels ----------------

__global__ __launch_bounds__(256) void cvt_pair(const float* __restrict__ in0,
                                                u16* __restrict__ out0,
                                                const float* __restrict__ in1,
                                                u16* __restrict__ out1, long n4)
{
    long i = blockIdx.x * 256L + threadIdx.x;
    const long stride = (long)gridDim.x * 256L;
    for (; i < 2 * n4; i += stride) {
        const float* in = (i < n4) ? in0 : in1;
        u16* out = (i < n4) ? out0 : out1;
        const long j = (i < n4) ? i : (i - n4);
        const float4 v = ((const float4*)in)[j];
        ushort4 o;
        o.x = f2bf(v.x); o.y = f2bf(v.y); o.z = f2bf(v.z); o.w = f2bf(v.w);
        ((ushort4*)out)[j] = o;
    }
}

// weight transposes (fp32 [K][N] -> bf16 [N][K])
__global__ __launch_bounds__(256) void prep_weights(
    const float* __restrict__ Wq, u16* __restrict__ WqT,
    const float* __restrict__ Wk, u16* __restrict__ WkT,
    const float* __restrict__ Wv, u16* __restrict__ WvT,
    const float* __restrict__ Wf, u16* __restrict__ WfT)
{
    const long e = blockIdx.x * 256L + threadIdx.x;
    if (e < 65536) {
        const long idx = e;              // Wq: K=512,N=128
        const long n = idx / 512, k = idx % 512;
        WqT[idx] = f2bf(Wq[k * 128 + n]);
    } else if (e < 131072) {
        const long idx = e - 65536;      // Wk
        const long n = idx / 512, k = idx % 512;
        WkT[idx] = f2bf(Wk[k * 128 + n]);
    } else if (e < 393216) {
        const long idx = e - 131072;     // Wv: K=512,N=512
        const long n = idx / 512, k = idx % 512;
        WvT[idx] = f2bf(Wv[k * 512 + n]);
    } else if (e < 917504) {
        const long idx = e - 393216;     // Wf: K=1024,N=512
        const long n = idx / 1024, k = idx % 1024;
        WfT[idx] = f2bf(Wf[k * 512 + n]);
    }
}

// ---------------- MFMA GEMM (projections / fusion / vT) ----------------
// A: bf16 [M][K]; B: bf16 [N][K]. DUAL: 0 plain batched; 1 concat-A; 2 z-select.
// EPI: 0 bf16 store +bias; 2 fp32 sigmoid store +bias.
// BIASM: 0 bias indexed by n (output col); 1 bias indexed by m (output row).
template <int DUAL, int EPI, int BIASM>
__global__ __launch_bounds__(256) void mfma_gemm(
    const u16* __restrict__ Ap, const u16* __restrict__ A2p, long lda,
    const u16* __restrict__ Bp, const u16* __restrict__ Bp2, long ldb,
    const float* __restrict__ biasp, const float* __restrict__ bias2,
    void* __restrict__ Cp, void* __restrict__ Cp2, long ldc, int K,
    long sA, long sB, long sC)
{
    __shared__ u16 smA[128 * 32];
    __shared__ u16 smB[128 * 32];

    const int tid  = threadIdx.x;
    const int lane = tid & 63;
    const int wid  = tid >> 6;
    const int wr   = wid >> 1;
    const int wc   = wid & 1;

    const long row0 = (long)blockIdx.y * 128;
    const long col0 = (long)blockIdx.x * 128;
    const long z    = blockIdx.z;

    const u16* Abase = (DUAL == 2) ? (z ? A2p : Ap) : (Ap + z * sA);
    const u16* Bbase = (DUAL == 2) ? (z ? Bp2 : Bp) : (Bp + z * sB);

    f32x4 acc[4][4];
#pragma unroll
    for (int i = 0; i < 4; ++i)
#pragma unroll
        for (int j = 0; j < 4; ++j)
            acc[i][j] = (f32x4){0.f, 0.f, 0.f, 0.f};

    const int lrow = (lane >> 4) * 4;
    const int lcol = lane & 15;
    const int q8   = (lane >> 4) * 8;

    for (int kb = 0; kb < K; kb += 32) {
#pragma unroll
        for (int rep = 0; rep < 2; ++rep) {
            const int c  = tid + rep * 256;
            const int r  = c >> 2;
            const int kc = (c & 3) * 8;
            const int wbase = (wid * 64 + rep * 256) * 8;
            const u16* ga;
            if (DUAL == 1 && (kb + kc) >= APF_D) {
                ga = A2p + (row0 + r) * lda + (kb + kc - APF_D);
            } else {
                ga = Abase + (row0 + r) * lda + (kb + kc);
            }
            load16_lds(ga, &smA[wbase]);
            const u16* gb = Bbase + (col0 + r) * ldb + (kb + kc);
            load16_lds(gb, &smB[wbase]);
        }
        __syncthreads();

        short8 av[4], bv4[4];
#pragma unroll
        for (int ti = 0; ti < 4; ++ti)
            av[ti] = *(const short8*)&smA[(wr * 64 + ti * 16 + lcol) * 32 + q8];
#pragma unroll
        for (int tj = 0; tj < 4; ++tj)
            bv4[tj] = *(const short8*)&smB[(wc * 64 + tj * 16 + lcol) * 32 + q8];

#pragma unroll
        for (int ti = 0; ti < 4; ++ti)
#pragma unroll
            for (int tj = 0; tj < 4; ++tj)
                acc[ti][tj] = __builtin_amdgcn_mfma_f32_16x16x32_bf16(
                    av[ti], bv4[tj], acc[ti][tj], 0, 0, 0);
        __syncthreads();
    }

    const float* bias = (DUAL == 2 && z) ? bias2 : biasp;

#pragma unroll
    for (int ti = 0; ti < 4; ++ti) {
        const long m0t = row0 + wr * 64 + ti * 16 + lrow;
#pragma unroll
        for (int tj = 0; tj < 4; ++tj) {
            const long n = col0 + wc * 64 + tj * 16 + lcol;
            const float bn = (BIASM == 0 && bias != nullptr) ? bias[n] : 0.f;
            if (EPI == 0) {
                u16* C = (u16*)((DUAL == 2 && z) ? Cp2 : Cp) + ((DUAL == 2) ? 0 : z * sC);
#pragma unroll
                for (int r = 0; r < 4; ++r) {
                    const float bm = (BIASM == 1) ? bias[m0t + r] : bn;
                    C[(m0t + r) * ldc + n] = f2bf(acc[ti][tj][r] + bm);
                }
            } else {
                float* C = (float*)Cp;
#pragma unroll
                for (int r = 0; r < 4; ++r) {
                    const float val = acc[ti][tj][r] + bn;
                    C[(m0t + r) * ldc + n] = 1.0f / (1.0f + expf(-val));
                }
            }
        }
    }
}

// ---------------- fused attention ----------------
// Grid (D-chunks=2, Q-tiles=32, B=8) = 512 blocks; 256 threads = 4 waves.
// Block: Q rows [q0,q0+64), out cols [d0,d0+256). Wave w owns Q rows
// [q0+16w, +16). Loop s-tiles of 64: S = Q@K^T (MFMA), P = exp(S) -> LDS
// (C->A layout hop), O += P@V (MFMA), rowsum in registers; normalize at end.
// LDS = 79.0 KB -> 2 blocks/CU (the R7 105KB/1-block config was
// lockstep-latency-bound at MfmaUtil 20%).
#define FA_LDQ 136
#define FA_LDK 136
#define FA_LDV 72
#define FA_LDP 72

__global__ __launch_bounds__(256, 2) void attn_fused(
    const u16* __restrict__ qg, const u16* __restrict__ kg,
    const u16* __restrict__ vTg, u16* __restrict__ attg)
{
    __shared__ u16 sQ[64 * FA_LDQ];
    __shared__ u16 sK[64 * FA_LDK];
    __shared__ u16 sV[256 * FA_LDV];
    __shared__ u16 sP[64 * FA_LDP];

    const int tid  = threadIdx.x;
    const int lane = tid & 63;
    const int w    = tid >> 6;       // 0..3
    const int l15  = lane & 15;
    const int q4   = lane >> 4;      // 0..3

    const long z  = blockIdx.z;
    const long q0 = (long)blockIdx.y * 64;
    const long d0 = (long)blockIdx.x * 256;

    // stage Q tile once (contiguous 64x128 u16)
    {
        const u16* src = qg + (z * APF_T + q0) * APF_H;
#pragma unroll
        for (int rep = 0; rep < 4; ++rep) {
            const int c   = tid + rep * 256;      // 0..1023
            const int row = c >> 4;
            const int c8  = (c & 15) * 8;
            *(uint4*)&sQ[row * FA_LDQ + c8] = *(const uint4*)(src + (long)c * 8);
        }
    }

    f32x4 oacc[16];
#pragma unroll
    for (int i = 0; i < 16; ++i) oacc[i] = (f32x4){0.f, 0.f, 0.f, 0.f};
    float rs[4] = {0.f, 0.f, 0.f, 0.f};

    for (int kt = 0; kt < APF_T / 64; ++kt) {
        __syncthreads();   // prev iter's sK/sV reads done (also covers sQ stage)
        // stage K tile (contiguous 64x128 u16)
        {
            const u16* src = kg + (z * APF_T + (long)kt * 64) * APF_H;
#pragma unroll
            for (int rep = 0; rep < 4; ++rep) {
                const int c   = tid + rep * 256;  // 0..1023
                const int row = c >> 4;
                const int c8  = (c & 15) * 8;
                *(uint4*)&sK[row * FA_LDK + c8] = *(const uint4*)(src + (long)c * 8);
            }
        }
        // stage V tile: sV[d][s] from vT[z][d0+d][kt*64+s]
        {
            const u16* src = vTg + z * ((long)APF_D * APF_T) + d0 * APF_T + (long)kt * 64;
#pragma unroll
            for (int rep = 0; rep < 8; ++rep) {
                const int c   = tid + rep * 256;  // 0..2047
                const int row = c >> 3;           // 0..255
                const int c8  = (c & 7) * 8;      // 0..56
                *(uint4*)&sV[row * FA_LDV + c8] =
                    *(const uint4*)(src + (long)row * APF_T + c8);
            }
        }
        __syncthreads();

        // S(16x64 per wave) = Q_w @ K_tile^T, contraction over h=128
        f32x4 sacc[4];
#pragma unroll
        for (int tj = 0; tj < 4; ++tj) sacc[tj] = (f32x4){0.f, 0.f, 0.f, 0.f};
#pragma unroll
        for (int kk = 0; kk < 4; ++kk) {
            const short8 av = *(const short8*)&sQ[(w * 16 + l15) * FA_LDQ + kk * 32 + q4 * 8];
#pragma unroll
            for (int tj = 0; tj < 4; ++tj) {
                const short8 bv = *(const short8*)&sK[(tj * 16 + l15) * FA_LDK + kk * 32 + q4 * 8];
                sacc[tj] = __builtin_amdgcn_mfma_f32_16x16x32_bf16(av, bv, sacc[tj], 0, 0, 0);
            }
        }
        // exp + rowsum + P to LDS (C-layout -> A-layout hop)
#pragma unroll
        for (int tj = 0; tj < 4; ++tj)
#pragma unroll
            for (int r = 0; r < 4; ++r) {
                const float e = __expf(sacc[tj][r]);
                rs[r] += e;
                sP[(w * 16 + q4 * 4 + r) * FA_LDP + tj * 16 + l15] = f2bf(e);
            }
        // O(16x256 per wave) += P_w(16x64) @ V(256x64)^T  (wave-local sP rows)
#pragma unroll
        for (int kk = 0; kk < 2; ++kk) {
            const short8 ap = *(const short8*)&sP[(w * 16 + l15) * FA_LDP + kk * 32 + q4 * 8];
#pragma unroll
            for (int dt = 0; dt < 16; ++dt) {
                const short8 bv = *(const short8*)&sV[(dt * 16 + l15) * FA_LDV + kk * 32 + q4 * 8];
                oacc[dt] = __builtin_amdgcn_mfma_f32_16x16x32_bf16(ap, bv, oacc[dt], 0, 0, 0);
            }
        }
    }

    // rowsum reduce across the 16 col-lanes (bits 0..3 of lane)
#pragma unroll
    for (int r = 0; r < 4; ++r) {
        float s = rs[r];
        s += __shfl_xor(s, 1);
        s += __shfl_xor(s, 2);
        s += __shfl_xor(s, 4);
        s += __shfl_xor(s, 8);
        rs[r] = 1.0f / s;
    }

    // store att rows
    const long mbase = z * APF_T + q0 + w * 16 + q4 * 4;
#pragma unroll
    for (int dt = 0; dt < 16; ++dt) {
        const long col = d0 + dt * 16 + l15;
#pragma unroll
        for (int r = 0; r < 4; ++r)
            attg[(mbase + r) * APF_D + col] = f2bf(oacc[dt][r] * rs[r]);
    }
}

extern "C" void kernel_launch(void* const* d_in, const int* in_sizes, int n_in,
                              void* d_out, int out_size, void* d_ws, size_t ws_size,
                              hipStream_t stream)
{
    (void)in_sizes; (void)n_in; (void)out_size; (void)ws_size;

    const float* x    = (const float*)d_in[0];
    const float* pred = (const float*)d_in[1];
    const float* Wq   = (const float*)d_in[2];
    const float* bq   = (const float*)d_in[3];
    const float* Wk   = (const float*)d_in[4];
    const float* bk   = (const float*)d_in[5];
    const float* Wv   = (const float*)d_in[6];
    const float* bv   = (const float*)d_in[7];
    const float* Wf   = (const float*)d_in[8];
    const float* bfu  = (const float*)d_in[9];

    // Workspace (u16), ~80 MB
    u16* wsp   = (u16*)d_ws;
    u16* xb    = wsp;                                  // [16384][512]
    u16* predb = xb    + (long)APF_M * APF_D;          // [16384][512]
    u16* qb    = predb + (long)APF_M * APF_D;          // [16384][128]
    u16* kbuf  = qb    + (long)APF_M * APF_H;          // [16384][128]
    u16* vTb   = kbuf  + (long)APF_M * APF_H;          // [8][512][2048]
    u16* attb  = vTb   + (long)APF_M * APF_D;          // [16384][512]
    u16* WqT   = attb  + (long)APF_M * APF_D;          // [128][512]
    u16* WkT   = WqT   + (long)APF_H * APF_D;          // [128][512]
    u16* WvT   = WkT   + (long)APF_H * APF_D;          // [512][512]
    u16* WfT   = WvT   + (long)APF_D * APF_D;          // [512][1024]

    const dim3 thr(256);
    const long nBTD4 = (long)APF_M * APF_D / 4;

    cvt_pair<<<dim3(1024), thr, 0, stream>>>(x, xb, pred, predb, nBTD4);
    prep_weights<<<dim3(3584), thr, 0, stream>>>(Wq, WqT, Wk, WkT, Wv, WvT, Wf, WfT);

    // q = pred@Wq+bq (z=0), k = x@Wk+bk (z=1)
    mfma_gemm<2, 0, 0><<<dim3(1, 128, 2), thr, 0, stream>>>(
        predb, xb, APF_D, WqT, WkT, APF_D, bq, bk, qb, kbuf, APF_H, APF_D,
        0, 0, 0);

    // vT[z] = WvT @ xb[z]^T + bv  (A=WvT M=512-d, B=xb N=s; bias on M;
    //  coalesced store, ldc=2048)
    mfma_gemm<0, 0, 1><<<dim3(16, 4, 8), thr, 0, stream>>>(
        WvT, nullptr, APF_D, xb, nullptr, APF_D, bv, nullptr, vTb, nullptr,
        APF_T, APF_D, 0, (long)APF_T * APF_D, (long)APF_D * APF_T);

    // fused attention: att = softmax(q k^T) v   (one kernel, no scores buffer)
    attn_fused<<<dim3(2, 32, 8), thr, 0, stream>>>(qb, kbuf, vTb, attb);

    // out = sigmoid([pred|att] @ Wf + bf) -> fp32 d_out
    mfma_gemm<1, 2, 0><<<dim3(4, 128, 1), thr, 0, stream>>>(
        predb, attb, APF_D, WfT, nullptr, 2 * APF_D, bfu, nullptr, d_out, nullptr,
        APF_D, 2 * APF_D, 0, 0, 0);
}